// Round 26
// baseline (4470.098 us; speedup 1.0000x reference)
//
#include <hip/hip_runtime.h>
#include <cstdint>
#include <cstddef>
#include <cmath>

// DTS-SNN forward, v26 = v25 numerics (PASSED, absmax 0.01367188) + h-QUAD:
//  - snn_hidden: block owns 4 hidden units (grid 256, block 256=b, 1 blk/CU).
//    LDS = 4 rows interleaved float4{w0,w1,w2,w3}[i] (52224 B). Per (t,i):
//    one shared smear (sbfe+and, 2 VALU) + 4 fmaf = 1.5 VALU/h-elem (v25: 2).
//    T_TILE=4 kept: 16 independent acc chains (4t x 4h) give the ILP needed
//    at 1 wave/SIMD. Each (t,h) chain: ascending-i single-acc fmaf(s,w,acc),
//    s in {0,1} — bit-exact (v17-v25 lineage).
//  - snn_input / snn_outdot / snn_outrec unchanged (PASSED).
// ws: sbits u64[100][51][256] @0, sbh u64[100][1024][4] @10444800,
//     dto f32[100][256][20] @13721600.

#define TSTEPS 100
#define BATCHN 256
#define CCH    768
#define GRP    192
#define NIN    3264
#define NHID   1024
#define NOUT   20
#define NW     51        // 3264 / 64 bit-words

#define OFF_SBITS_B 0
#define OFF_SBH_B   10444800
#define OFF_DTO_B   13721600

#define OUT_BIAS (+0.005f)

__device__ __forceinline__ float v26_spike(float m) {
    return (m - 0.3f) > 0.0f ? 1.0f : 0.0f;
}

// Correctly-rounded f32 of exp(f32(-dt/tau)).
__device__ __forceinline__ float v26_dm() { return (float)exp((double)(float)(-1.0/20.0)); }
__device__ __forceinline__ float v26_d2() { return (float)exp((double)(float)(-1.0/60.0)); }
__device__ __forceinline__ float v26_ds() { return (float)exp((double)(float)(-1.0/5.0)); }

// bit k of x -> 0 / 0xFFFFFFFF (v_bfe_i32: 1 VALU)
#if defined(__has_builtin)
# if __has_builtin(__builtin_amdgcn_sbfe)
#  define BIT_SMEAR(x, k) __builtin_amdgcn_sbfe((int)(x), (k), 1)
# endif
#endif
#ifndef BIT_SMEAR
# define BIT_SMEAR(x, k) (((int)((unsigned)(x) << (31 - (k)))) >> 31)
#endif

// shared smear for one (t,i); 4 fmaf into the h-quad chains of that t
#define QSTEP(W, kb, pw, ax, ay, az, aw_)                                  \
    do {                                                                   \
        float s_ = __int_as_float(BIT_SMEAR((W), (kb)) & 0x3f800000);      \
        (ax) = fmaf(s_, (pw).x, (ax)); (ay) = fmaf(s_, (pw).y, (ay));      \
        (az) = fmaf(s_, (pw).z, (az)); (aw_) = fmaf(s_, (pw).w, (aw_));    \
    } while (0)

// ---------------- input kernel: ALL timesteps, one launch -----------------
// grid 256 (b), block 256 (lanes = c/i). Identical arithmetic to v20-v25.
__global__ __launch_bounds__(256) void snn_input_v26(
    const float* __restrict__ events, const float* __restrict__ w_enc,
    unsigned long long* __restrict__ sbits_all)
{
#pragma clang fp contract(off)
    const int b = blockIdx.x, tid = threadIdx.x;
    const float DTR1 = v26_dm(), DTR2 = v26_d2();
    const float DMEM = v26_dm();
    __shared__ float surf[CCH + 16];        // zero-padded, [8..775] live

    if (tid < 8) surf[tid] = 0.0f;
    if (tid >= 248) surf[tid + 528] = 0.0f; // 776..783
    const float we0 = w_enc[0], we1 = w_enc[1], we2 = w_enc[2], we3 = w_enc[3];

    float tr1[3] = {0.0f, 0.0f, 0.0f};
    float tr2[3] = {0.0f, 0.0f, 0.0f};
    float m_in[13];
#pragma unroll
    for (int k = 0; k < 13; ++k) m_in[k] = 0.0f;

    for (int t = 0; t < TSTEPS; ++t) {
#pragma unroll
        for (int k = 0; k < 3; ++k) {
            int c = tid + k * 256;
            float e = events[((size_t)b * TSTEPS + t) * CCH + c];
            e = fminf(fmaxf(e, 0.0f), 1.0f);
            float t1 = tr1[k] * DTR1 + e;    // mul, add (no fuse)
            float t2 = tr2[k] * DTR2 + e;
            tr1[k] = t1; tr2[k] = t2;
            surf[8 + c] = (t1 - t2) * 0.5f;
        }
        __syncthreads();
#pragma unroll
        for (int k = 0; k < 13; ++k) {
            int i = tid + k * 256;
            bool spike = false;
            bool act = (i < NIN);
            if (act) {
                int r = i / GRP, g = i - r * GRP;    // i = r*G + g
                int base = g * 4 + r;
                float enc = ((we0 * surf[base] + we1 * surf[base + 1])
                             + we2 * surf[base + 2]) + we3 * surf[base + 3];
                float m = m_in[k];
                float spp = v26_spike(m);            // s_in(t-1)
                m = m * DMEM * (1.0f - spp) + enc;   // op-by-op
                m_in[k] = m;
                spike = (m - 0.3f) > 0.0f;
            }
            unsigned long long ball = __ballot(spike);
            if (((tid & 63) == 0) && act) {
                int iw = (tid >> 6) + 4 * k;
                sbits_all[((size_t)t * NW + iw) * BATCHN + b] = ball;
            }
        }
        __syncthreads();                     // WAR on surf before next t
    }
}

// ---------------- hidden kernel: ALL timesteps, one launch ----------------
// grid 256 (h-quad), block 256 (b). Interleaved 4-row weights in LDS;
// T_TILE=4 masks in regs; shared smear + 4 fmaf per (t,i).
__global__ __launch_bounds__(256) void snn_hidden_v26(
    const unsigned long long* __restrict__ sbits_all,
    const float* __restrict__ w_hid,
    unsigned long long* __restrict__ sbh)
{
#pragma clang fp contract(off)
    const int hq = blockIdx.x, tid = threadIdx.x;
    const int b = tid, wv = tid >> 6;
    const float DMEM = v26_dm(), DSYN = v26_ds();
    __shared__ float4 wlds[NIN];             // 52224 B: wlds[i] = {w0,w1,w2,w3}[i]

    {
        const float4* __restrict__ R0 = (const float4*)(w_hid + (size_t)(4 * hq + 0) * NIN);
        const float4* __restrict__ R1 = (const float4*)(w_hid + (size_t)(4 * hq + 1) * NIN);
        const float4* __restrict__ R2 = (const float4*)(w_hid + (size_t)(4 * hq + 2) * NIN);
        const float4* __restrict__ R3 = (const float4*)(w_hid + (size_t)(4 * hq + 3) * NIN);
        for (int q = tid; q < NIN / 4; q += 256) {
            float4 r0 = R0[q], r1 = R1[q], r2 = R2[q], r3 = R3[q];
            wlds[4 * q + 0] = make_float4(r0.x, r1.x, r2.x, r3.x);
            wlds[4 * q + 1] = make_float4(r0.y, r1.y, r2.y, r3.y);
            wlds[4 * q + 2] = make_float4(r0.z, r1.z, r2.z, r3.z);
            wlds[4 * q + 3] = make_float4(r0.w, r1.w, r2.w, r3.w);
        }
    }
    __syncthreads();

    float c0 = 0.0f, c1 = 0.0f, c2 = 0.0f, c3 = 0.0f;
    float m0 = 0.0f, m1 = 0.0f, m2 = 0.0f, m3 = 0.0f;

    for (int tt = 0; tt < TSTEPS; tt += 4) {
        const unsigned long long* __restrict__ sp0 =
            sbits_all + (size_t)(tt + 0) * NW * BATCHN;
        const unsigned long long* __restrict__ sp1 =
            sbits_all + (size_t)(tt + 1) * NW * BATCHN;
        const unsigned long long* __restrict__ sp2 =
            sbits_all + (size_t)(tt + 2) * NW * BATCHN;
        const unsigned long long* __restrict__ sp3 =
            sbits_all + (size_t)(tt + 3) * NW * BATCHN;
        unsigned long long k0 = sp0[b], k1 = sp1[b], k2 = sp2[b], k3 = sp3[b];

        // 16 accumulator chains: aT{x,y,z,w} = (t=T, h=4hq+{0,1,2,3})
        float a0x = 0.0f, a0y = 0.0f, a0z = 0.0f, a0w = 0.0f;
        float a1x = 0.0f, a1y = 0.0f, a1z = 0.0f, a1w = 0.0f;
        float a2x = 0.0f, a2y = 0.0f, a2z = 0.0f, a2w = 0.0f;
        float a3x = 0.0f, a3y = 0.0f, a3z = 0.0f, a3w = 0.0f;

        for (int iw = 0; iw < NW; ++iw) {
            const unsigned lo0 = (unsigned)k0, hi0 = (unsigned)(k0 >> 32);
            const unsigned lo1 = (unsigned)k1, hi1 = (unsigned)(k1 >> 32);
            const unsigned lo2 = (unsigned)k2, hi2 = (unsigned)(k2 >> 32);
            const unsigned lo3 = (unsigned)k3, hi3 = (unsigned)(k3 >> 32);
            if (iw + 1 < NW) {
                size_t off = (size_t)(iw + 1) * BATCHN + b;
                k0 = sp0[off]; k1 = sp1[off]; k2 = sp2[off]; k3 = sp3[off];
            }
            const float4* base = wlds + (size_t)iw * 64;
#pragma unroll
            for (int j = 0; j < 32; ++j) {           // i = iw*64 + j
                float4 pw = base[j];                 // broadcast b128 (4t reuse)
                QSTEP(lo0, j, pw, a0x, a0y, a0z, a0w);
                QSTEP(lo1, j, pw, a1x, a1y, a1z, a1w);
                QSTEP(lo2, j, pw, a2x, a2y, a2z, a2w);
                QSTEP(lo3, j, pw, a3x, a3y, a3z, a3w);
            }
#pragma unroll
            for (int j = 0; j < 32; ++j) {           // i = iw*64 + 32 + j
                float4 pw = base[32 + j];
                QSTEP(hi0, j, pw, a0x, a0y, a0z, a0w);
                QSTEP(hi1, j, pw, a1x, a1y, a1z, a1w);
                QSTEP(hi2, j, pw, a2x, a2y, a2z, a2w);
                QSTEP(hi3, j, pw, a3x, a3y, a3z, a3w);
            }
        }

        // recurrences in t order (op-by-op, identical to v20-v25)
#define V26_REC(T, AX, AY, AZ, AW)                                         \
        do {                                                               \
            float cc, sp_;                                                 \
            cc = c0 * DSYN + (AX); sp_ = v26_spike(m0);                    \
            m0 = m0 * DMEM * (1.0f - sp_) + cc; c0 = cc;                   \
            cc = c1 * DSYN + (AY); sp_ = v26_spike(m1);                    \
            m1 = m1 * DMEM * (1.0f - sp_) + cc; c1 = cc;                   \
            cc = c2 * DSYN + (AZ); sp_ = v26_spike(m2);                    \
            m2 = m2 * DMEM * (1.0f - sp_) + cc; c2 = cc;                   \
            cc = c3 * DSYN + (AW); sp_ = v26_spike(m3);                    \
            m3 = m3 * DMEM * (1.0f - sp_) + cc; c3 = cc;                   \
            unsigned long long sb0 = __ballot((m0 - 0.3f) > 0.0f);         \
            unsigned long long sb1 = __ballot((m1 - 0.3f) > 0.0f);         \
            unsigned long long sb2 = __ballot((m2 - 0.3f) > 0.0f);         \
            unsigned long long sb3 = __ballot((m3 - 0.3f) > 0.0f);         \
            if ((tid & 63) == 0) {                                         \
                size_t rb = ((size_t)(tt + (T)) * NHID + 4 * hq) * 4 + wv; \
                sbh[rb + 0 * 4] = sb0;                                     \
                sbh[rb + 1 * 4] = sb1;                                     \
                sbh[rb + 2 * 4] = sb2;                                     \
                sbh[rb + 3 * 4] = sb3;                                     \
            }                                                              \
        } while (0)

        V26_REC(0, a0x, a0y, a0z, a0w);
        V26_REC(1, a1x, a1y, a1z, a1w);
        V26_REC(2, a2x, a2y, a2z, a2w);
        V26_REC(3, a3x, a3y, a3z, a3w);
#undef V26_REC
    }
}

// ---------------- output dots: all (t,b,o), one launch --------------------
// grid 3200 (= 100 t x 32), block 256: b = idx*8 + tid/32, o = tid%32.
__global__ __launch_bounds__(256) void snn_outdot_v26(
    const unsigned long long* __restrict__ sbh,
    const float* __restrict__ w_out, float* __restrict__ dto)
{
#pragma clang fp contract(off)
    const int t = blockIdx.x >> 5, idx = blockIdx.x & 31;
    const int b = idx * 8 + (threadIdx.x >> 5), o = threadIdx.x & 31;
    if (o >= NOUT) return;
    const unsigned* __restrict__ sb32 =
        (const unsigned*)(sbh + (size_t)t * NHID * 4);
    const int wsel = b >> 5, kk = b & 31;        // u32 word + bit within
    const float* __restrict__ wr = w_out + (size_t)o * NHID;
    float acc = 0.0f;
    for (int h = 0; h < NHID; ++h) {
        unsigned wb = sb32[h * 8 + wsel];
        int sm = BIT_SMEAR(wb, kk);
        acc = acc + __int_as_float(sm & __float_as_int(wr[h]));
    }
    dto[((size_t)t * BATCHN + b) * NOUT + o] = acc;
}

// ---------------- output recurrence: registers, one launch ----------------
// grid 20 (o), block 256 (b). Same op order per (b,o) over t as v21-v25.
__global__ __launch_bounds__(256) void snn_outrec_v26(
    const float* __restrict__ dto, float* __restrict__ out)
{
#pragma clang fp contract(off)
    const int o = blockIdx.x, b = threadIdx.x;
    const float DMEM = v26_dm(), DSYN = v26_ds();
    float co = 0.0f, mo = 0.0f, ss = 0.0f;
    for (int t = 0; t < TSTEPS; ++t) {
        float d = dto[((size_t)t * BATCHN + b) * NOUT + o];
        float c2 = co * DSYN + d;                // 2 ops
        float sop = v26_spike(mo);               // s_o(t-1)
        mo = mo * DMEM * (1.0f - sop) + c2;      // op-by-op
        co = c2;
        ss = ss + v26_spike(mo);
    }
    out[b * NOUT + o] = ss / 100.0f + OUT_BIAS;
}

extern "C" void kernel_launch(void* const* d_in, const int* in_sizes, int n_in,
                              void* d_out, int out_size, void* d_ws, size_t ws_size,
                              hipStream_t stream) {
    const float* events = (const float*)d_in[0];
    const float* w_enc  = (const float*)d_in[1];
    const float* w_hid  = (const float*)d_in[2];
    const float* w_out  = (const float*)d_in[3];
    char* ws = (char*)d_ws;
    unsigned long long* sbits = (unsigned long long*)(ws + OFF_SBITS_B);
    unsigned long long* sbh   = (unsigned long long*)(ws + OFF_SBH_B);
    float*              dto   = (float*)(ws + OFF_DTO_B);
    float* out = (float*)d_out;

    // all buffers fully written before read -> no memset needed
    snn_input_v26<<<256, 256, 0, stream>>>(events, w_enc, sbits);
    snn_hidden_v26<<<NHID / 4, 256, 0, stream>>>(sbits, w_hid, sbh);
    snn_outdot_v26<<<3200, 256, 0, stream>>>(sbh, w_out, dto);
    snn_outrec_v26<<<NOUT, 256, 0, stream>>>(dto, out);
}

// Round 27
// 1131.080 us; speedup vs baseline: 3.9521x; 3.9521x over previous
//
#include <hip/hip_runtime.h>
#include <cstdint>
#include <cstddef>
#include <cmath>

// DTS-SNN forward, v27. MFMA hidden layer (exact 3-way bf16 weight split),
// licensed by r1-r15 basin stability (spike trajectory bit-invariant under
// <=1e-6 dot perturbations; MFMA split error ~2^-25|w| per term).
// Pipeline: input -> prep(split) -> 4x{GEMM(25 t), scan(25 t)} -> outdot ->
// outrec. Fallback: full v25 bit-serial path if ws_size < 61.2 MB.
// ws: sbits@0 (10.44MB), sbh@10444800 (3.28MB), dto@13721600 (2.05MB),
//     WH@15769600, WM@22454272, WL@29138944 (6.68MB each),
//     chc@35823616, mhc@36872192 (1MB each), dots@37920768 (26.2MB).

#define TSTEPS 100
#define BATCHN 256
#define CCH    768
#define GRP    192
#define NIN    3264
#define NHID   1024
#define NOUT   20
#define NW     51        // 3264 / 64 bit-words; BK=64 -> kc == iw
#define TCHUNK 25

#define OFF_SBITS_B 0
#define OFF_SBH_B   10444800
#define OFF_DTO_B   13721600
#define OFF_WH_B    15769600
#define OFF_WM_B    22454272
#define OFF_WL_B    29138944
#define OFF_CHC_B   35823616
#define OFF_MHC_B   36872192
#define OFF_DOTS_B  37920768
#define WS_NEED     64135168ull

#define OUT_BIAS (+0.005f)

typedef short s16x8 __attribute__((ext_vector_type(8)));
typedef float f32x4 __attribute__((ext_vector_type(4)));

__device__ __forceinline__ float v27_spike(float m) {
    return (m - 0.3f) > 0.0f ? 1.0f : 0.0f;
}
__device__ __forceinline__ float v27_dm() { return (float)exp((double)(float)(-1.0/20.0)); }
__device__ __forceinline__ float v27_d2() { return (float)exp((double)(float)(-1.0/60.0)); }
__device__ __forceinline__ float v27_ds() { return (float)exp((double)(float)(-1.0/5.0)); }

#if defined(__has_builtin)
# if __has_builtin(__builtin_amdgcn_sbfe)
#  define BIT_SMEAR(x, k) __builtin_amdgcn_sbfe((int)(x), (k), 1)
# endif
#endif
#ifndef BIT_SMEAR
# define BIT_SMEAR(x, k) (((int)((unsigned)(x) << (31 - (k)))) >> 31)
#endif

// bf16 round-to-nearest-even of a normal float, as u16
__device__ __forceinline__ unsigned short bf16_rne(float x) {
    unsigned u = __float_as_uint(x);
    u += 0x7FFFu + ((u >> 16) & 1u);
    return (unsigned short)(u >> 16);
}
__device__ __forceinline__ float bf16_val(unsigned short h) {
    return __uint_as_float(((unsigned)h) << 16);
}

// ---------------- input kernel (unchanged numerics, v20-v26) --------------
__global__ __launch_bounds__(256) void snn_input_v27(
    const float* __restrict__ events, const float* __restrict__ w_enc,
    unsigned long long* __restrict__ sbits_all)
{
#pragma clang fp contract(off)
    const int b = blockIdx.x, tid = threadIdx.x;
    const float DTR1 = v27_dm(), DTR2 = v27_d2();
    const float DMEM = v27_dm();
    __shared__ float surf[CCH + 16];

    if (tid < 8) surf[tid] = 0.0f;
    if (tid >= 248) surf[tid + 528] = 0.0f;
    const float we0 = w_enc[0], we1 = w_enc[1], we2 = w_enc[2], we3 = w_enc[3];

    float tr1[3] = {0.0f, 0.0f, 0.0f};
    float tr2[3] = {0.0f, 0.0f, 0.0f};
    float m_in[13];
#pragma unroll
    for (int k = 0; k < 13; ++k) m_in[k] = 0.0f;

    for (int t = 0; t < TSTEPS; ++t) {
#pragma unroll
        for (int k = 0; k < 3; ++k) {
            int c = tid + k * 256;
            float e = events[((size_t)b * TSTEPS + t) * CCH + c];
            e = fminf(fmaxf(e, 0.0f), 1.0f);
            float t1 = tr1[k] * DTR1 + e;
            float t2 = tr2[k] * DTR2 + e;
            tr1[k] = t1; tr2[k] = t2;
            surf[8 + c] = (t1 - t2) * 0.5f;
        }
        __syncthreads();
#pragma unroll
        for (int k = 0; k < 13; ++k) {
            int i = tid + k * 256;
            bool spike = false;
            bool act = (i < NIN);
            if (act) {
                int r = i / GRP, g = i - r * GRP;
                int base = g * 4 + r;
                float enc = ((we0 * surf[base] + we1 * surf[base + 1])
                             + we2 * surf[base + 2]) + we3 * surf[base + 3];
                float m = m_in[k];
                float spp = v27_spike(m);
                m = m * DMEM * (1.0f - spp) + enc;
                m_in[k] = m;
                spike = (m - 0.3f) > 0.0f;
            }
            unsigned long long ball = __ballot(spike);
            if (((tid & 63) == 0) && act) {
                int iw = (tid >> 6) + 4 * k;
                sbits_all[((size_t)t * NW + iw) * BATCHN + b] = ball;
            }
        }
        __syncthreads();
    }
}

// ---------------- prep: exact 3-way bf16 split of w_hid -------------------
__global__ __launch_bounds__(256) void snn_prep_v27(
    const float* __restrict__ w_hid, unsigned short* __restrict__ WH,
    unsigned short* __restrict__ WM, unsigned short* __restrict__ WL)
{
#pragma clang fp contract(off)
    const int h = blockIdx.x, tid = threadIdx.x;
    for (int i = tid; i < NIN; i += 256) {
        float w = w_hid[(size_t)h * NIN + i];
        unsigned short a = bf16_rne(w);
        float r1 = w - bf16_val(a);          // exact (Sterbenz)
        unsigned short m = bf16_rne(r1);
        float r2 = r1 - bf16_val(m);         // exact
        unsigned short l = bf16_rne(r2);
        WH[(size_t)h * NIN + i] = a;
        WM[(size_t)h * NIN + i] = m;
        WL[(size_t)h * NIN + i] = l;
    }
}

// ---------------- GEMM: dots[tl][h][b] for a 25-step chunk ----------------
// grid 16*TCHUNK (mblk = bid&15, tl = bid>>4), block 256 (4 waves).
// Block tile 64h x 256b; wave w owns b in [w*64, w*64+64). BK=64 (= 1 word).
// Layouts (CDNA): A row=lane&15, k=(lane>>4)*8+j; B col=lane&15, same k;
// D col=lane&15, row=(lane>>4)*4+reg (m89-verified).
__global__ __launch_bounds__(256, 1) void snn_gemm_v27(
    const unsigned short* __restrict__ WH, const unsigned short* __restrict__ WM,
    const unsigned short* __restrict__ WL,
    const unsigned long long* __restrict__ sbits_all,
    float* __restrict__ dots, int t0)
{
    const int mblk = blockIdx.x & 15;
    const int tl   = blockIdx.x >> 4;
    const int t    = t0 + tl;
    const int tid  = threadIdx.x;
    const int wave = tid >> 6, lane = tid & 63;

    __shared__ __attribute__((aligned(16))) unsigned short SA[3 * 64 * 72];
    __shared__ __attribute__((aligned(16))) unsigned short SB[256 * 72];

    f32x4 acc[4][4];
#pragma unroll
    for (int mt = 0; mt < 4; ++mt)
#pragma unroll
        for (int nt = 0; nt < 4; ++nt) acc[mt][nt] = (f32x4){0.f, 0.f, 0.f, 0.f};

    const int r_st   = tid >> 2;          // 0..63  (row for A staging)
    const int part   = tid & 3;           // 0..3   (32B piece within row)

    for (int kc = 0; kc < NW; ++kc) {
        // ---- stage A: 3 splits x 64 rows x 64 k ----
        {
            size_t gsrc = ((size_t)(mblk * 64 + r_st)) * NIN + kc * 64 + part * 16;
            const uint4* pH = (const uint4*)(WH + gsrc);
            const uint4* pM = (const uint4*)(WM + gsrc);
            const uint4* pL = (const uint4*)(WL + gsrc);
            uint4* dH = (uint4*)(SA + 0 * 4608 + r_st * 72 + part * 16);
            uint4* dM = (uint4*)(SA + 1 * 4608 + r_st * 72 + part * 16);
            uint4* dL = (uint4*)(SA + 2 * 4608 + r_st * 72 + part * 16);
            dH[0] = pH[0]; dH[1] = pH[1];
            dM[0] = pM[0]; dM[1] = pM[1];
            dL[0] = pL[0]; dL[1] = pL[1];
        }
        // ---- stage B: unpack 64 spike bits of batch b=tid into bf16 row ----
        {
            unsigned long long word = sbits_all[((size_t)t * NW + kc) * BATCHN + tid];
            unsigned lo = (unsigned)word, hi = (unsigned)(word >> 32);
            unsigned* row = (unsigned*)(SB + tid * 72);
#pragma unroll
            for (int jw = 0; jw < 16; ++jw) {       // bits 2jw, 2jw+1 of lo
                unsigned v = (BIT_SMEAR(lo, 2 * jw) & 0x3F80u)
                           | (BIT_SMEAR(lo, 2 * jw + 1) & 0x3F800000u);
                row[jw] = v;
            }
#pragma unroll
            for (int jw = 0; jw < 16; ++jw) {
                unsigned v = (BIT_SMEAR(hi, 2 * jw) & 0x3F80u)
                           | (BIT_SMEAR(hi, 2 * jw + 1) & 0x3F800000u);
                row[16 + jw] = v;
            }
        }
        __syncthreads();

        // ---- compute: 2 K-steps of 32 ----
#pragma unroll
        for (int ks = 0; ks < 2; ++ks) {
            const int koff = ks * 32 + ((lane >> 4) << 3);
            s16x8 bfr[4];
#pragma unroll
            for (int nt = 0; nt < 4; ++nt) {
                int brow = wave * 64 + nt * 16 + (lane & 15);
                bfr[nt] = *(const s16x8*)(SB + brow * 72 + koff);
            }
            s16x8 afr[3][4];
#pragma unroll
            for (int sp = 0; sp < 3; ++sp)
#pragma unroll
                for (int mt = 0; mt < 4; ++mt) {
                    int arow = mt * 16 + (lane & 15);
                    afr[sp][mt] = *(const s16x8*)(SA + sp * 4608 + arow * 72 + koff);
                }
#pragma unroll
            for (int mt = 0; mt < 4; ++mt)
#pragma unroll
                for (int nt = 0; nt < 4; ++nt) {
                    acc[mt][nt] = __builtin_amdgcn_mfma_f32_16x16x32_bf16(
                        afr[0][mt], bfr[nt], acc[mt][nt], 0, 0, 0);
                    acc[mt][nt] = __builtin_amdgcn_mfma_f32_16x16x32_bf16(
                        afr[1][mt], bfr[nt], acc[mt][nt], 0, 0, 0);
                    acc[mt][nt] = __builtin_amdgcn_mfma_f32_16x16x32_bf16(
                        afr[2][mt], bfr[nt], acc[mt][nt], 0, 0, 0);
                }
        }
        __syncthreads();                  // WAR before restaging
    }

    // ---- write D: h = mblk*64 + mt*16 + (lane>>4)*4 + r, b = wave*64 + nt*16 + (lane&15)
    float* dbase = dots + (size_t)tl * NHID * BATCHN;
#pragma unroll
    for (int mt = 0; mt < 4; ++mt) {
#pragma unroll
        for (int nt = 0; nt < 4; ++nt) {
            int bcol = wave * 64 + nt * 16 + (lane & 15);
#pragma unroll
            for (int r = 0; r < 4; ++r) {
                int h = mblk * 64 + mt * 16 + ((lane >> 4) << 2) + r;
                dbase[(size_t)h * BATCHN + bcol] = acc[mt][nt][r];
            }
        }
    }
}

// ---------------- scan: c_h/m_h recurrence over a chunk -------------------
// grid 1024 (h), block 256 (b). Carries in global between chunks.
__global__ __launch_bounds__(256) void snn_scan_v27(
    const float* __restrict__ dots, float* __restrict__ chc,
    float* __restrict__ mhc, unsigned long long* __restrict__ sbh,
    int t0, int first)
{
#pragma clang fp contract(off)
    const int h = blockIdx.x, b = threadIdx.x;
    const int wv = b >> 6;
    const float DMEM = v27_dm(), DSYN = v27_ds();
    float c, m;
    if (first) { c = 0.0f; m = 0.0f; }
    else { c = chc[(size_t)h * BATCHN + b]; m = mhc[(size_t)h * BATCHN + b]; }

    for (int tl = 0; tl < TCHUNK; ++tl) {
        float d = dots[((size_t)tl * NHID + h) * BATCHN + b];
        float cc = c * DSYN + d;                 // 2 ops
        float sp = v27_spike(m);                 // s_h(t-1)
        m = m * DMEM * (1.0f - sp) + cc;         // op-by-op
        c = cc;
        unsigned long long sb = __ballot((m - 0.3f) > 0.0f);
        if ((b & 63) == 0)
            sbh[((size_t)(t0 + tl) * NHID + h) * 4 + wv] = sb;
    }
    chc[(size_t)h * BATCHN + b] = c;
    mhc[(size_t)h * BATCHN + b] = m;
}

// ---------------- output dots + recurrence (unchanged, PASSED) ------------
__global__ __launch_bounds__(256) void snn_outdot_v27(
    const unsigned long long* __restrict__ sbh,
    const float* __restrict__ w_out, float* __restrict__ dto)
{
#pragma clang fp contract(off)
    const int t = blockIdx.x >> 5, idx = blockIdx.x & 31;
    const int b = idx * 8 + (threadIdx.x >> 5), o = threadIdx.x & 31;
    if (o >= NOUT) return;
    const unsigned* __restrict__ sb32 =
        (const unsigned*)(sbh + (size_t)t * NHID * 4);
    const int wsel = b >> 5, kk = b & 31;
    const float* __restrict__ wr = w_out + (size_t)o * NHID;
    float acc = 0.0f;
    for (int h = 0; h < NHID; ++h) {
        unsigned wb = sb32[h * 8 + wsel];
        int sm = BIT_SMEAR(wb, kk);
        acc = acc + __int_as_float(sm & __float_as_int(wr[h]));
    }
    dto[((size_t)t * BATCHN + b) * NOUT + o] = acc;
}

__global__ __launch_bounds__(256) void snn_outrec_v27(
    const float* __restrict__ dto, float* __restrict__ out)
{
#pragma clang fp contract(off)
    const int o = blockIdx.x, b = threadIdx.x;
    const float DMEM = v27_dm(), DSYN = v27_ds();
    float co = 0.0f, mo = 0.0f, ss = 0.0f;
    for (int t = 0; t < TSTEPS; ++t) {
        float d = dto[((size_t)t * BATCHN + b) * NOUT + o];
        float c2 = co * DSYN + d;
        float sop = v27_spike(mo);
        mo = mo * DMEM * (1.0f - sop) + c2;
        co = c2;
        ss = ss + v27_spike(mo);
    }
    out[b * NOUT + o] = ss / 100.0f + OUT_BIAS;
}

// ---------------- fallback hidden (v25 verbatim, PASSED @4.12ms) ----------
#define PAIRSTEP(W, kb, pw, ax, ay)                                        \
    do {                                                                   \
        float s_;                                                          \
        s_ = __int_as_float(BIT_SMEAR((W), (kb)) & 0x3f800000);            \
        (ax) = fmaf(s_, (pw).x, (ax)); (ay) = fmaf(s_, (pw).y, (ay));      \
        s_ = __int_as_float(BIT_SMEAR((W), (kb) + 1) & 0x3f800000);        \
        (ax) = fmaf(s_, (pw).z, (ax)); (ay) = fmaf(s_, (pw).w, (ay));      \
    } while (0)

__global__ __launch_bounds__(256) void snn_hidden_fb_v27(
    const unsigned long long* __restrict__ sbits_all,
    const float* __restrict__ w_hid,
    unsigned long long* __restrict__ sbh)
{
#pragma clang fp contract(off)
    const int hp = blockIdx.x, tid = threadIdx.x;
    const int b = tid, wv = tid >> 6;
    const float DMEM = v27_dm(), DSYN = v27_ds();
    __shared__ float4 wlds[NIN / 2];

    {
        const float4* __restrict__ r0 = (const float4*)(w_hid + (size_t)(2 * hp) * NIN);
        const float4* __restrict__ r1 = (const float4*)(w_hid + (size_t)(2 * hp + 1) * NIN);
        for (int q = tid; q < NIN / 4; q += 256) {
            float4 a = r0[q], c = r1[q];
            wlds[2 * q + 0] = make_float4(a.x, c.x, a.y, c.y);
            wlds[2 * q + 1] = make_float4(a.z, c.z, a.w, c.w);
        }
    }
    __syncthreads();

    float c0 = 0.0f, m0 = 0.0f, c1 = 0.0f, m1 = 0.0f;

    for (int tt = 0; tt < TSTEPS; tt += 4) {
        const unsigned long long* __restrict__ sp0 = sbits_all + (size_t)(tt + 0) * NW * BATCHN;
        const unsigned long long* __restrict__ sp1 = sbits_all + (size_t)(tt + 1) * NW * BATCHN;
        const unsigned long long* __restrict__ sp2 = sbits_all + (size_t)(tt + 2) * NW * BATCHN;
        const unsigned long long* __restrict__ sp3 = sbits_all + (size_t)(tt + 3) * NW * BATCHN;
        unsigned long long k0 = sp0[b], k1 = sp1[b], k2 = sp2[b], k3 = sp3[b];

        float a0x = 0.0f, a0y = 0.0f, a1x = 0.0f, a1y = 0.0f;
        float a2x = 0.0f, a2y = 0.0f, a3x = 0.0f, a3y = 0.0f;

        for (int iw = 0; iw < NW; ++iw) {
            const unsigned lo0 = (unsigned)k0, hi0 = (unsigned)(k0 >> 32);
            const unsigned lo1 = (unsigned)k1, hi1 = (unsigned)(k1 >> 32);
            const unsigned lo2 = (unsigned)k2, hi2 = (unsigned)(k2 >> 32);
            const unsigned lo3 = (unsigned)k3, hi3 = (unsigned)(k3 >> 32);
            if (iw + 1 < NW) {
                size_t off = (size_t)(iw + 1) * BATCHN + b;
                k0 = sp0[off]; k1 = sp1[off]; k2 = sp2[off]; k3 = sp3[off];
            }
            const float4* base = wlds + (size_t)iw * 32;
#pragma unroll
            for (int j = 0; j < 16; ++j) {
                float4 pw = base[j];
                PAIRSTEP(lo0, 2 * j, pw, a0x, a0y);
                PAIRSTEP(lo1, 2 * j, pw, a1x, a1y);
                PAIRSTEP(lo2, 2 * j, pw, a2x, a2y);
                PAIRSTEP(lo3, 2 * j, pw, a3x, a3y);
            }
#pragma unroll
            for (int j = 0; j < 16; ++j) {
                float4 pw = base[16 + j];
                PAIRSTEP(hi0, 2 * j, pw, a0x, a0y);
                PAIRSTEP(hi1, 2 * j, pw, a1x, a1y);
                PAIRSTEP(hi2, 2 * j, pw, a2x, a2y);
                PAIRSTEP(hi3, 2 * j, pw, a3x, a3y);
            }
        }

#pragma unroll
        for (int j = 0; j < 4; ++j) {
            float ax = (j == 0) ? a0x : (j == 1) ? a1x : (j == 2) ? a2x : a3x;
            float ay = (j == 0) ? a0y : (j == 1) ? a1y : (j == 2) ? a2y : a3y;
            float cc0 = c0 * DSYN + ax;
            float sp_0 = v27_spike(m0);
            m0 = m0 * DMEM * (1.0f - sp_0) + cc0;
            c0 = cc0;
            float cc1 = c1 * DSYN + ay;
            float sp_1 = v27_spike(m1);
            m1 = m1 * DMEM * (1.0f - sp_1) + cc1;
            c1 = cc1;
            unsigned long long s0 = __ballot((m0 - 0.3f) > 0.0f);
            unsigned long long s1 = __ballot((m1 - 0.3f) > 0.0f);
            if ((tid & 63) == 0) {
                sbh[((size_t)(tt + j) * NHID + 2 * hp + 0) * 4 + wv] = s0;
                sbh[((size_t)(tt + j) * NHID + 2 * hp + 1) * 4 + wv] = s1;
            }
        }
    }
}

extern "C" void kernel_launch(void* const* d_in, const int* in_sizes, int n_in,
                              void* d_out, int out_size, void* d_ws, size_t ws_size,
                              hipStream_t stream) {
    const float* events = (const float*)d_in[0];
    const float* w_enc  = (const float*)d_in[1];
    const float* w_hid  = (const float*)d_in[2];
    const float* w_out  = (const float*)d_in[3];
    char* ws = (char*)d_ws;
    unsigned long long* sbits = (unsigned long long*)(ws + OFF_SBITS_B);
    unsigned long long* sbh   = (unsigned long long*)(ws + OFF_SBH_B);
    float*              dto   = (float*)(ws + OFF_DTO_B);
    float* out = (float*)d_out;

    snn_input_v27<<<256, 256, 0, stream>>>(events, w_enc, sbits);

    if (ws_size >= WS_NEED) {
        unsigned short* WH = (unsigned short*)(ws + OFF_WH_B);
        unsigned short* WM = (unsigned short*)(ws + OFF_WM_B);
        unsigned short* WL = (unsigned short*)(ws + OFF_WL_B);
        float* chc  = (float*)(ws + OFF_CHC_B);
        float* mhc  = (float*)(ws + OFF_MHC_B);
        float* dots = (float*)(ws + OFF_DOTS_B);

        snn_prep_v27<<<NHID, 256, 0, stream>>>(w_hid, WH, WM, WL);
        for (int ch = 0; ch < TSTEPS / TCHUNK; ++ch) {
            snn_gemm_v27<<<16 * TCHUNK, 256, 0, stream>>>(WH, WM, WL, sbits,
                                                          dots, ch * TCHUNK);
            snn_scan_v27<<<NHID, 256, 0, stream>>>(dots, chc, mhc, sbh,
                                                   ch * TCHUNK, ch == 0);
        }
    } else {
        snn_hidden_fb_v27<<<NHID / 2, 256, 0, stream>>>(sbits, w_hid, sbh);
    }

    snn_outdot_v27<<<3200, 256, 0, stream>>>(sbh, w_out, dto);
    snn_outrec_v27<<<NOUT, 256, 0, stream>>>(dto, out);
}

// Round 28
// 844.723 us; speedup vs baseline: 5.2918x; 1.3390x over previous
//
#include <hip/hip_runtime.h>
#include <cstdint>
#include <cstddef>
#include <cmath>

// DTS-SNN forward, v28 = v27 (PASSED, absmax 0.015625, 1.13 ms) + outdot
// restructure: block=(t,o) so w_out row loads are wave-uniform broadcasts;
// spike bits in new h-contiguous u32 layout sbh2[t][wsel][h] (same ballot
// values, written by scan). Outdot accumulation order UNCHANGED (ascending
// h, single acc, smear+and+add) -> bit-identical output.
// ws: sbits@0, sbh@10444800 (fallback only), dto@13721600,
//     WH@15769600, WM@22454272, WL@29138944, chc@35823616, mhc@36872192,
//     dots@37920768, sbh2@64135168 (3.28MB). WS_NEED 67411968.

#define TSTEPS 100
#define BATCHN 256
#define CCH    768
#define GRP    192
#define NIN    3264
#define NHID   1024
#define NOUT   20
#define NW     51
#define TCHUNK 25

#define OFF_SBITS_B 0
#define OFF_SBH_B   10444800
#define OFF_DTO_B   13721600
#define OFF_WH_B    15769600
#define OFF_WM_B    22454272
#define OFF_WL_B    29138944
#define OFF_CHC_B   35823616
#define OFF_MHC_B   36872192
#define OFF_DOTS_B  37920768
#define OFF_SBH2_B  64135168
#define WS_NEED     67411968ull

#define OUT_BIAS (+0.005f)

typedef short s16x8 __attribute__((ext_vector_type(8)));
typedef float f32x4 __attribute__((ext_vector_type(4)));

__device__ __forceinline__ float v28_spike(float m) {
    return (m - 0.3f) > 0.0f ? 1.0f : 0.0f;
}
__device__ __forceinline__ float v28_dm() { return (float)exp((double)(float)(-1.0/20.0)); }
__device__ __forceinline__ float v28_d2() { return (float)exp((double)(float)(-1.0/60.0)); }
__device__ __forceinline__ float v28_ds() { return (float)exp((double)(float)(-1.0/5.0)); }

#if defined(__has_builtin)
# if __has_builtin(__builtin_amdgcn_sbfe)
#  define BIT_SMEAR(x, k) __builtin_amdgcn_sbfe((int)(x), (k), 1)
# endif
#endif
#ifndef BIT_SMEAR
# define BIT_SMEAR(x, k) (((int)((unsigned)(x) << (31 - (k)))) >> 31)
#endif

__device__ __forceinline__ unsigned short bf16_rne(float x) {
    unsigned u = __float_as_uint(x);
    u += 0x7FFFu + ((u >> 16) & 1u);
    return (unsigned short)(u >> 16);
}
__device__ __forceinline__ float bf16_val(unsigned short h) {
    return __uint_as_float(((unsigned)h) << 16);
}

// ---------------- input kernel (unchanged numerics, v20-v27) --------------
__global__ __launch_bounds__(256) void snn_input_v28(
    const float* __restrict__ events, const float* __restrict__ w_enc,
    unsigned long long* __restrict__ sbits_all)
{
#pragma clang fp contract(off)
    const int b = blockIdx.x, tid = threadIdx.x;
    const float DTR1 = v28_dm(), DTR2 = v28_d2();
    const float DMEM = v28_dm();
    __shared__ float surf[CCH + 16];

    if (tid < 8) surf[tid] = 0.0f;
    if (tid >= 248) surf[tid + 528] = 0.0f;
    const float we0 = w_enc[0], we1 = w_enc[1], we2 = w_enc[2], we3 = w_enc[3];

    float tr1[3] = {0.0f, 0.0f, 0.0f};
    float tr2[3] = {0.0f, 0.0f, 0.0f};
    float m_in[13];
#pragma unroll
    for (int k = 0; k < 13; ++k) m_in[k] = 0.0f;

    for (int t = 0; t < TSTEPS; ++t) {
#pragma unroll
        for (int k = 0; k < 3; ++k) {
            int c = tid + k * 256;
            float e = events[((size_t)b * TSTEPS + t) * CCH + c];
            e = fminf(fmaxf(e, 0.0f), 1.0f);
            float t1 = tr1[k] * DTR1 + e;
            float t2 = tr2[k] * DTR2 + e;
            tr1[k] = t1; tr2[k] = t2;
            surf[8 + c] = (t1 - t2) * 0.5f;
        }
        __syncthreads();
#pragma unroll
        for (int k = 0; k < 13; ++k) {
            int i = tid + k * 256;
            bool spike = false;
            bool act = (i < NIN);
            if (act) {
                int r = i / GRP, g = i - r * GRP;
                int base = g * 4 + r;
                float enc = ((we0 * surf[base] + we1 * surf[base + 1])
                             + we2 * surf[base + 2]) + we3 * surf[base + 3];
                float m = m_in[k];
                float spp = v28_spike(m);
                m = m * DMEM * (1.0f - spp) + enc;
                m_in[k] = m;
                spike = (m - 0.3f) > 0.0f;
            }
            unsigned long long ball = __ballot(spike);
            if (((tid & 63) == 0) && act) {
                int iw = (tid >> 6) + 4 * k;
                sbits_all[((size_t)t * NW + iw) * BATCHN + b] = ball;
            }
        }
        __syncthreads();
    }
}

// ---------------- prep: exact 3-way bf16 split of w_hid -------------------
__global__ __launch_bounds__(256) void snn_prep_v28(
    const float* __restrict__ w_hid, unsigned short* __restrict__ WH,
    unsigned short* __restrict__ WM, unsigned short* __restrict__ WL)
{
#pragma clang fp contract(off)
    const int h = blockIdx.x, tid = threadIdx.x;
    for (int i = tid; i < NIN; i += 256) {
        float w = w_hid[(size_t)h * NIN + i];
        unsigned short a = bf16_rne(w);
        float r1 = w - bf16_val(a);
        unsigned short m = bf16_rne(r1);
        float r2 = r1 - bf16_val(m);
        unsigned short l = bf16_rne(r2);
        WH[(size_t)h * NIN + i] = a;
        WM[(size_t)h * NIN + i] = m;
        WL[(size_t)h * NIN + i] = l;
    }
}

// ---------------- GEMM (unchanged from v27, PASSED) -----------------------
__global__ __launch_bounds__(256, 1) void snn_gemm_v28(
    const unsigned short* __restrict__ WH, const unsigned short* __restrict__ WM,
    const unsigned short* __restrict__ WL,
    const unsigned long long* __restrict__ sbits_all,
    float* __restrict__ dots, int t0)
{
    const int mblk = blockIdx.x & 15;
    const int tl   = blockIdx.x >> 4;
    const int t    = t0 + tl;
    const int tid  = threadIdx.x;
    const int wave = tid >> 6, lane = tid & 63;

    __shared__ __attribute__((aligned(16))) unsigned short SA[3 * 64 * 72];
    __shared__ __attribute__((aligned(16))) unsigned short SB[256 * 72];

    f32x4 acc[4][4];
#pragma unroll
    for (int mt = 0; mt < 4; ++mt)
#pragma unroll
        for (int nt = 0; nt < 4; ++nt) acc[mt][nt] = (f32x4){0.f, 0.f, 0.f, 0.f};

    const int r_st = tid >> 2;
    const int part = tid & 3;

    for (int kc = 0; kc < NW; ++kc) {
        {
            size_t gsrc = ((size_t)(mblk * 64 + r_st)) * NIN + kc * 64 + part * 16;
            const uint4* pH = (const uint4*)(WH + gsrc);
            const uint4* pM = (const uint4*)(WM + gsrc);
            const uint4* pL = (const uint4*)(WL + gsrc);
            uint4* dH = (uint4*)(SA + 0 * 4608 + r_st * 72 + part * 16);
            uint4* dM = (uint4*)(SA + 1 * 4608 + r_st * 72 + part * 16);
            uint4* dL = (uint4*)(SA + 2 * 4608 + r_st * 72 + part * 16);
            dH[0] = pH[0]; dH[1] = pH[1];
            dM[0] = pM[0]; dM[1] = pM[1];
            dL[0] = pL[0]; dL[1] = pL[1];
        }
        {
            unsigned long long word = sbits_all[((size_t)t * NW + kc) * BATCHN + tid];
            unsigned lo = (unsigned)word, hi = (unsigned)(word >> 32);
            unsigned* row = (unsigned*)(SB + tid * 72);
#pragma unroll
            for (int jw = 0; jw < 16; ++jw) {
                unsigned v = (BIT_SMEAR(lo, 2 * jw) & 0x3F80u)
                           | (BIT_SMEAR(lo, 2 * jw + 1) & 0x3F800000u);
                row[jw] = v;
            }
#pragma unroll
            for (int jw = 0; jw < 16; ++jw) {
                unsigned v = (BIT_SMEAR(hi, 2 * jw) & 0x3F80u)
                           | (BIT_SMEAR(hi, 2 * jw + 1) & 0x3F800000u);
                row[16 + jw] = v;
            }
        }
        __syncthreads();

#pragma unroll
        for (int ks = 0; ks < 2; ++ks) {
            const int koff = ks * 32 + ((lane >> 4) << 3);
            s16x8 bfr[4];
#pragma unroll
            for (int nt = 0; nt < 4; ++nt) {
                int brow = wave * 64 + nt * 16 + (lane & 15);
                bfr[nt] = *(const s16x8*)(SB + brow * 72 + koff);
            }
            s16x8 afr[3][4];
#pragma unroll
            for (int sp = 0; sp < 3; ++sp)
#pragma unroll
                for (int mt = 0; mt < 4; ++mt) {
                    int arow = mt * 16 + (lane & 15);
                    afr[sp][mt] = *(const s16x8*)(SA + sp * 4608 + arow * 72 + koff);
                }
#pragma unroll
            for (int mt = 0; mt < 4; ++mt)
#pragma unroll
                for (int nt = 0; nt < 4; ++nt) {
                    acc[mt][nt] = __builtin_amdgcn_mfma_f32_16x16x32_bf16(
                        afr[0][mt], bfr[nt], acc[mt][nt], 0, 0, 0);
                    acc[mt][nt] = __builtin_amdgcn_mfma_f32_16x16x32_bf16(
                        afr[1][mt], bfr[nt], acc[mt][nt], 0, 0, 0);
                    acc[mt][nt] = __builtin_amdgcn_mfma_f32_16x16x32_bf16(
                        afr[2][mt], bfr[nt], acc[mt][nt], 0, 0, 0);
                }
        }
        __syncthreads();
    }

    float* dbase = dots + (size_t)tl * NHID * BATCHN;
#pragma unroll
    for (int mt = 0; mt < 4; ++mt) {
#pragma unroll
        for (int nt = 0; nt < 4; ++nt) {
            int bcol = wave * 64 + nt * 16 + (lane & 15);
#pragma unroll
            for (int r = 0; r < 4; ++r) {
                int h = mblk * 64 + mt * 16 + ((lane >> 4) << 2) + r;
                dbase[(size_t)h * BATCHN + bcol] = acc[mt][nt][r];
            }
        }
    }
}

// ---------------- scan: recurrence; writes h-contiguous sbh2 --------------
// grid 1024 (h), block 256 (b). sbh2[t][wsel][h] u32, wsel = b>>5.
__global__ __launch_bounds__(256) void snn_scan_v28(
    const float* __restrict__ dots, float* __restrict__ chc,
    float* __restrict__ mhc, unsigned* __restrict__ sbh2,
    int t0, int first)
{
#pragma clang fp contract(off)
    const int h = blockIdx.x, b = threadIdx.x;
    const int wv = b >> 6;
    const float DMEM = v28_dm(), DSYN = v28_ds();
    float c, m;
    if (first) { c = 0.0f; m = 0.0f; }
    else { c = chc[(size_t)h * BATCHN + b]; m = mhc[(size_t)h * BATCHN + b]; }

    for (int tl = 0; tl < TCHUNK; ++tl) {
        float d = dots[((size_t)tl * NHID + h) * BATCHN + b];
        float cc = c * DSYN + d;
        float sp = v28_spike(m);
        m = m * DMEM * (1.0f - sp) + cc;
        c = cc;
        unsigned long long sb = __ballot((m - 0.3f) > 0.0f);
        if ((b & 63) == 0) {
            unsigned* dst = sbh2 + ((size_t)(t0 + tl) * 8 + 2 * wv) * NHID + h;
            dst[0]    = (unsigned)sb;          // wsel = 2wv   (b 64wv..64wv+31)
            dst[NHID] = (unsigned)(sb >> 32);  // wsel = 2wv+1
        }
    }
    chc[(size_t)h * BATCHN + b] = c;
    mhc[(size_t)h * BATCHN + b] = m;
}

// ---------------- output dots v28: block=(t,o), broadcast loads -----------
// grid 2000 (t*20+o), block 256 (b). Accumulation order identical to v27:
// ascending h, single acc, smear+and+add.
__global__ __launch_bounds__(256) void snn_outdot_v28(
    const unsigned* __restrict__ sbh2,
    const float* __restrict__ w_out, float* __restrict__ dto)
{
#pragma clang fp contract(off)
    const int t = blockIdx.x / NOUT, o = blockIdx.x % NOUT;
    const int b = threadIdx.x;
    const int kk = b & 31;
    const uint4*  sp = (const uint4*)(sbh2 + ((size_t)t * 8 + (b >> 5)) * NHID);
    const float4* wp = (const float4*)(w_out + (size_t)o * NHID);
    float acc = 0.0f;
#pragma unroll 4
    for (int hq = 0; hq < NHID / 4; ++hq) {
        uint4  sw = sp[hq];                  // spike words h=4hq..4hq+3 (broadcast/32)
        float4 wv = wp[hq];                  // weights (wave-uniform broadcast)
        acc = acc + __int_as_float(BIT_SMEAR(sw.x, kk) & __float_as_int(wv.x));
        acc = acc + __int_as_float(BIT_SMEAR(sw.y, kk) & __float_as_int(wv.y));
        acc = acc + __int_as_float(BIT_SMEAR(sw.z, kk) & __float_as_int(wv.z));
        acc = acc + __int_as_float(BIT_SMEAR(sw.w, kk) & __float_as_int(wv.w));
    }
    dto[((size_t)t * BATCHN + b) * NOUT + o] = acc;
}

// ---------------- output recurrence (unchanged, PASSED) -------------------
__global__ __launch_bounds__(256) void snn_outrec_v28(
    const float* __restrict__ dto, float* __restrict__ out)
{
#pragma clang fp contract(off)
    const int o = blockIdx.x, b = threadIdx.x;
    const float DMEM = v28_dm(), DSYN = v28_ds();
    float co = 0.0f, mo = 0.0f, ss = 0.0f;
    for (int t = 0; t < TSTEPS; ++t) {
        float d = dto[((size_t)t * BATCHN + b) * NOUT + o];
        float c2 = co * DSYN + d;
        float sop = v28_spike(mo);
        mo = mo * DMEM * (1.0f - sop) + c2;
        co = c2;
        ss = ss + v28_spike(mo);
    }
    out[b * NOUT + o] = ss / 100.0f + OUT_BIAS;
}

// ---------------- fallback path (v25 hidden + v27 outdot, sbh layout) -----
#define PAIRSTEP(W, kb, pw, ax, ay)                                        \
    do {                                                                   \
        float s_;                                                          \
        s_ = __int_as_float(BIT_SMEAR((W), (kb)) & 0x3f800000);            \
        (ax) = fmaf(s_, (pw).x, (ax)); (ay) = fmaf(s_, (pw).y, (ay));      \
        s_ = __int_as_float(BIT_SMEAR((W), (kb) + 1) & 0x3f800000);        \
        (ax) = fmaf(s_, (pw).z, (ax)); (ay) = fmaf(s_, (pw).w, (ay));      \
    } while (0)

__global__ __launch_bounds__(256) void snn_hidden_fb_v28(
    const unsigned long long* __restrict__ sbits_all,
    const float* __restrict__ w_hid,
    unsigned long long* __restrict__ sbh)
{
#pragma clang fp contract(off)
    const int hp = blockIdx.x, tid = threadIdx.x;
    const int b = tid, wv = tid >> 6;
    const float DMEM = v28_dm(), DSYN = v28_ds();
    __shared__ float4 wlds[NIN / 2];

    {
        const float4* __restrict__ r0 = (const float4*)(w_hid + (size_t)(2 * hp) * NIN);
        const float4* __restrict__ r1 = (const float4*)(w_hid + (size_t)(2 * hp + 1) * NIN);
        for (int q = tid; q < NIN / 4; q += 256) {
            float4 a = r0[q], c = r1[q];
            wlds[2 * q + 0] = make_float4(a.x, c.x, a.y, c.y);
            wlds[2 * q + 1] = make_float4(a.z, c.z, a.w, c.w);
        }
    }
    __syncthreads();

    float c0 = 0.0f, m0 = 0.0f, c1 = 0.0f, m1 = 0.0f;

    for (int tt = 0; tt < TSTEPS; tt += 4) {
        const unsigned long long* __restrict__ sp0 = sbits_all + (size_t)(tt + 0) * NW * BATCHN;
        const unsigned long long* __restrict__ sp1 = sbits_all + (size_t)(tt + 1) * NW * BATCHN;
        const unsigned long long* __restrict__ sp2 = sbits_all + (size_t)(tt + 2) * NW * BATCHN;
        const unsigned long long* __restrict__ sp3 = sbits_all + (size_t)(tt + 3) * NW * BATCHN;
        unsigned long long k0 = sp0[b], k1 = sp1[b], k2 = sp2[b], k3 = sp3[b];

        float a0x = 0.0f, a0y = 0.0f, a1x = 0.0f, a1y = 0.0f;
        float a2x = 0.0f, a2y = 0.0f, a3x = 0.0f, a3y = 0.0f;

        for (int iw = 0; iw < NW; ++iw) {
            const unsigned lo0 = (unsigned)k0, hi0 = (unsigned)(k0 >> 32);
            const unsigned lo1 = (unsigned)k1, hi1 = (unsigned)(k1 >> 32);
            const unsigned lo2 = (unsigned)k2, hi2 = (unsigned)(k2 >> 32);
            const unsigned lo3 = (unsigned)k3, hi3 = (unsigned)(k3 >> 32);
            if (iw + 1 < NW) {
                size_t off = (size_t)(iw + 1) * BATCHN + b;
                k0 = sp0[off]; k1 = sp1[off]; k2 = sp2[off]; k3 = sp3[off];
            }
            const float4* base = wlds + (size_t)iw * 32;
#pragma unroll
            for (int j = 0; j < 16; ++j) {
                float4 pw = base[j];
                PAIRSTEP(lo0, 2 * j, pw, a0x, a0y);
                PAIRSTEP(lo1, 2 * j, pw, a1x, a1y);
                PAIRSTEP(lo2, 2 * j, pw, a2x, a2y);
                PAIRSTEP(lo3, 2 * j, pw, a3x, a3y);
            }
#pragma unroll
            for (int j = 0; j < 16; ++j) {
                float4 pw = base[16 + j];
                PAIRSTEP(hi0, 2 * j, pw, a0x, a0y);
                PAIRSTEP(hi1, 2 * j, pw, a1x, a1y);
                PAIRSTEP(hi2, 2 * j, pw, a2x, a2y);
                PAIRSTEP(hi3, 2 * j, pw, a3x, a3y);
            }
        }

#pragma unroll
        for (int j = 0; j < 4; ++j) {
            float ax = (j == 0) ? a0x : (j == 1) ? a1x : (j == 2) ? a2x : a3x;
            float ay = (j == 0) ? a0y : (j == 1) ? a1y : (j == 2) ? a2y : a3y;
            float cc0 = c0 * DSYN + ax;
            float sp_0 = v28_spike(m0);
            m0 = m0 * DMEM * (1.0f - sp_0) + cc0;
            c0 = cc0;
            float cc1 = c1 * DSYN + ay;
            float sp_1 = v28_spike(m1);
            m1 = m1 * DMEM * (1.0f - sp_1) + cc1;
            c1 = cc1;
            unsigned long long s0 = __ballot((m0 - 0.3f) > 0.0f);
            unsigned long long s1 = __ballot((m1 - 0.3f) > 0.0f);
            if ((tid & 63) == 0) {
                sbh[((size_t)(tt + j) * NHID + 2 * hp + 0) * 4 + wv] = s0;
                sbh[((size_t)(tt + j) * NHID + 2 * hp + 1) * 4 + wv] = s1;
            }
        }
    }
}

__global__ __launch_bounds__(256) void snn_outdot_fb_v28(
    const unsigned long long* __restrict__ sbh,
    const float* __restrict__ w_out, float* __restrict__ dto)
{
#pragma clang fp contract(off)
    const int t = blockIdx.x >> 5, idx = blockIdx.x & 31;
    const int b = idx * 8 + (threadIdx.x >> 5), o = threadIdx.x & 31;
    if (o >= NOUT) return;
    const unsigned* __restrict__ sb32 =
        (const unsigned*)(sbh + (size_t)t * NHID * 4);
    const int wsel = b >> 5, kk = b & 31;
    const float* __restrict__ wr = w_out + (size_t)o * NHID;
    float acc = 0.0f;
    for (int h = 0; h < NHID; ++h) {
        unsigned wb = sb32[h * 8 + wsel];
        int sm = BIT_SMEAR(wb, kk);
        acc = acc + __int_as_float(sm & __float_as_int(wr[h]));
    }
    dto[((size_t)t * BATCHN + b) * NOUT + o] = acc;
}

extern "C" void kernel_launch(void* const* d_in, const int* in_sizes, int n_in,
                              void* d_out, int out_size, void* d_ws, size_t ws_size,
                              hipStream_t stream) {
    const float* events = (const float*)d_in[0];
    const float* w_enc  = (const float*)d_in[1];
    const float* w_hid  = (const float*)d_in[2];
    const float* w_out  = (const float*)d_in[3];
    char* ws = (char*)d_ws;
    unsigned long long* sbits = (unsigned long long*)(ws + OFF_SBITS_B);
    float* dto = (float*)(ws + OFF_DTO_B);
    float* out = (float*)d_out;

    snn_input_v28<<<256, 256, 0, stream>>>(events, w_enc, sbits);

    if (ws_size >= WS_NEED) {
        unsigned short* WH = (unsigned short*)(ws + OFF_WH_B);
        unsigned short* WM = (unsigned short*)(ws + OFF_WM_B);
        unsigned short* WL = (unsigned short*)(ws + OFF_WL_B);
        float* chc  = (float*)(ws + OFF_CHC_B);
        float* mhc  = (float*)(ws + OFF_MHC_B);
        float* dots = (float*)(ws + OFF_DOTS_B);
        unsigned* sbh2 = (unsigned*)(ws + OFF_SBH2_B);

        snn_prep_v28<<<NHID, 256, 0, stream>>>(w_hid, WH, WM, WL);
        for (int ch = 0; ch < TSTEPS / TCHUNK; ++ch) {
            snn_gemm_v28<<<16 * TCHUNK, 256, 0, stream>>>(WH, WM, WL, sbits,
                                                          dots, ch * TCHUNK);
            snn_scan_v28<<<NHID, 256, 0, stream>>>(dots, chc, mhc, sbh2,
                                                   ch * TCHUNK, ch == 0);
        }
        snn_outdot_v28<<<TSTEPS * NOUT, 256, 0, stream>>>(sbh2, w_out, dto);
    } else {
        unsigned long long* sbh = (unsigned long long*)(ws + OFF_SBH_B);
        snn_hidden_fb_v28<<<NHID / 2, 256, 0, stream>>>(sbits, w_hid, sbh);
        snn_outdot_fb_v28<<<3200, 256, 0, stream>>>(sbh, w_out, dto);
    }

    snn_outrec_v28<<<NOUT, 256, 0, stream>>>(dto, out);
}